// Round 17
// baseline (1298.285 us; speedup 1.0000x reference)
//
#include <hip/hip_runtime.h>

// ---------------- problem constants ----------------
#define N_NODES 50000
#define N_EDGES 800000
#define P_PERT  4
#define NTOT    (P_PERT * N_NODES)   // 200000
#define HDIM    64
#define NGRAPH  512
#define NCLASS  10
#define BN_EPS  1e-5f
#define SCAN_BLOCKS ((N_NODES + 255) / 256)   // 196
#define BN_SLICES 32
#define SAH_STRIDE 72  // halves; 144B rows, 16B-aligned frag reads, 2-way bank alias max
#define SC_STRIDE 72   // halves
#define GATHER_GRID (N_NODES / 8)   // 6250 blocks, 2 nodes/wave
#define ZERO_FLOATS 280752          // 1123008 bytes zeroed at ws start

typedef _Float16 half4 __attribute__((ext_vector_type(4)));
typedef _Float16 f16x8 __attribute__((ext_vector_type(8)));
typedef float    f32x4 __attribute__((ext_vector_type(4)));

// Graph structure is P-independent; offset == N (verified empirically in R1).
// Gather: 2 nodes/wave + 8-deep unroll (VGPR 40, ~54% occ) is the empirical
// optimum (R15 16-deep: VGPR 60 -> occ 37% regressed; R10 edge-balancing
// regressed). FETCH floor 188 MB @ ~3.5 TB/s — converged.
// R13 lesson: hwh MUST be 512B-aligned (64B-align cost 1.25x FETCH).
// R11 lesson: sBatch LDS staging diverged post-timing; batch[] via registers ok.
// R17: bn_reduce folded into gather last block (fence+ticket); memset folded
// into wpack — dispatch-count reduction.

// ---------------- CSR build ----------------

__global__ void count_kernel(const int* __restrict__ ei, int* __restrict__ cnt) {
    int j = blockIdx.x * blockDim.x + threadIdx.x;
    if (j >= N_EDGES) return;
    atomicAdd(&cnt[ei[N_EDGES + j]], 1);
}

__global__ void scan_reduce(const int* __restrict__ cnt, int* __restrict__ bsum,
                            float* __restrict__ dinv) {
    __shared__ int sdata[256];
    int i = blockIdx.x * 256 + threadIdx.x;
    int v = (i < N_NODES) ? cnt[i] : 0;
    if (i < N_NODES) dinv[i] = rsqrtf((float)v + 1.0f);
    sdata[threadIdx.x] = v;
    __syncthreads();
    for (int off = 128; off > 0; off >>= 1) {
        if (threadIdx.x < off) sdata[threadIdx.x] += sdata[threadIdx.x + off];
        __syncthreads();
    }
    if (threadIdx.x == 0) bsum[blockIdx.x] = sdata[0];
}

__global__ void scan_tops(const int* __restrict__ bsum, int* __restrict__ boff,
                          int* __restrict__ rowptr) {
    __shared__ int sdata[256];
    int t = threadIdx.x;
    int v = (t < SCAN_BLOCKS) ? bsum[t] : 0;
    sdata[t] = v;
    __syncthreads();
    for (int off = 1; off < 256; off <<= 1) {
        int tmp = (t >= off) ? sdata[t - off] : 0;
        __syncthreads();
        sdata[t] += tmp;
        __syncthreads();
    }
    if (t < SCAN_BLOCKS) boff[t] = sdata[t] - v;
    if (t == 255) rowptr[N_NODES] = sdata[255];
}

__global__ void scan_write(const int* __restrict__ cnt, const int* __restrict__ boff,
                           int* __restrict__ rowptr) {
    __shared__ int sdata[256];
    int i = blockIdx.x * 256 + threadIdx.x;
    int v = (i < N_NODES) ? cnt[i] : 0;
    sdata[threadIdx.x] = v;
    __syncthreads();
    for (int off = 1; off < 256; off <<= 1) {
        int tmp = (threadIdx.x >= off) ? sdata[threadIdx.x - off] : 0;
        __syncthreads();
        sdata[threadIdx.x] += tmp;
        __syncthreads();
    }
    if (i < N_NODES) rowptr[i] = boff[blockIdx.x] + sdata[threadIdx.x] - v;
}

__global__ void fill_kernel(const int* __restrict__ ei, const int* __restrict__ rowptr,
                            int* __restrict__ cursor, const float* __restrict__ dinv,
                            int2* __restrict__ csr) {
    int j = blockIdx.x * blockDim.x + threadIdx.x;
    if (j >= N_EDGES) return;
    int s = ei[j], d = ei[N_EDGES + j];
    int pos = rowptr[d] + atomicAdd(&cursor[d], 1);
    csr[pos] = make_int2(s, __float_as_int(dinv[s] * dinv[d]));
}

// repack conv_w into B-fragment order (fp16) AND zero the ws accumulator region
__global__ void wpack_zero_kernel(const float* __restrict__ W, _Float16* __restrict__ wpack,
                                  float* __restrict__ zreg) {
    int idx = blockIdx.x * 256 + threadIdx.x;
    if (idx < 4 * 4096) {
        int e = idx & 4095;
        int j = e & 7;
        int lane = (e >> 3) & 63;
        int ntkh = e >> 9;
        int kh = ntkh >> 2, nt = ntkh & 3;
        int m = lane & 15, quad = lane >> 4;
        wpack[idx] = (_Float16)W[(idx >> 12) * 4096 + (kh * 32 + quad * 8 + j) * 64 + nt * 16 + m];
    }
    for (int i = idx; i < ZERO_FLOATS; i += gridDim.x * 256) zreg[i] = 0.0f;
}

// ---------------- fused GEMM (MFMA, packed W) ----------------
template <int LAYER0>
__global__ __launch_bounds__(256) void gemm_fused(const void* __restrict__ srcv,
        const int* __restrict__ mask, const float* __restrict__ bnss,
        const int* __restrict__ batch, const _Float16* __restrict__ wpack,
        _Float16* __restrict__ hwh, float* __restrict__ pooled) {
    __shared__ _Float16 sAh[64 * SAH_STRIDE];
    __shared__ _Float16 sC[64 * SC_STRIDE];
    int tid = threadIdx.x;
    size_t rowbase = (size_t)blockIdx.x * 64;
    int lane = tid & 63;
    int wv = tid >> 6;
    // batch values for this wave's 16 pooled rows: wave-uniform scalar loads,
    // issued up-front so latency hides under A-staging + MFMA.
    int bg[16];
#pragma unroll
    for (int rr = 0; rr < 16; ++rr)
        bg[rr] = batch[(int)((rowbase + wv * 16 + rr) % N_NODES)];
    // B frags: coalesced f16x8 loads from packed W (16 KB, L2-hot)
    const f16x8* wp = (const f16x8*)wpack;
    f16x8 bfrag[2][4];
#pragma unroll
    for (int kh = 0; kh < 2; ++kh)
#pragma unroll
        for (int nt = 0; nt < 4; ++nt)
            bfrag[kh][nt] = wp[(kh * 4 + nt) * 64 + lane];
    // A staging (fp16): thread -> (row r0 + it*16, features f4..f4+3)
    int r0 = tid >> 4;
    int f4l = (tid & 15) * 4;
    float4 sc4, sh4;
    if (!LAYER0) {
        sc4 = *(const float4*)&bnss[f4l];
        sh4 = *(const float4*)&bnss[64 + f4l];
    }
#pragma unroll
    for (int it = 0; it < 4; ++it) {
        int r = r0 + it * 16;
        int grow = (int)rowbase + r;
        float4 val;
        if (LAYER0) {
            const float* src = (const float*)srcv;
            int p = grow / N_NODES, v = grow - p * N_NODES;
            if (mask[p * N_NODES + v]) {
                val = make_float4(0.f, 0.f, 0.f, 0.f);
            } else {
                val = *(const float4*)&src[(size_t)v * HDIM + f4l];
            }
        } else {
            const _Float16* src = (const _Float16*)srcv;
            half4 hv = *(const half4*)&src[(size_t)grow * HDIM + f4l];
            val.x = fmaxf((float)hv.x * sc4.x + sh4.x, 0.0f);
            val.y = fmaxf((float)hv.y * sc4.y + sh4.y, 0.0f);
            val.z = fmaxf((float)hv.z * sc4.z + sh4.z, 0.0f);
            val.w = fmaxf((float)hv.w * sc4.w + sh4.w, 0.0f);
        }
        half4 hv4 = {(_Float16)val.x, (_Float16)val.y, (_Float16)val.z, (_Float16)val.w};
        *(half4*)&sAh[r * SAH_STRIDE + f4l] = hv4;
    }
    __syncthreads();
    // MFMA: wave wv owns rows wv*16..wv*16+15; A-frag = one ds_read_b128 per kh
    int m = lane & 15;
    int quad = lane >> 4;
    f32x4 acc4[4];
#pragma unroll
    for (int nt = 0; nt < 4; ++nt) acc4[nt] = (f32x4){0.f, 0.f, 0.f, 0.f};
#pragma unroll
    for (int kh = 0; kh < 2; ++kh) {
        f16x8 a = *(const f16x8*)&sAh[(wv * 16 + m) * SAH_STRIDE + kh * 32 + quad * 8];
#pragma unroll
        for (int nt = 0; nt < 4; ++nt)
            acc4[nt] = __builtin_amdgcn_mfma_f32_16x16x32_f16(a, bfrag[kh][nt], acc4[nt], 0, 0, 0);
    }
    // C frag layout: col = nt*16+m, row(in 16-tile) = quad*4+reg -> stage to sC
#pragma unroll
    for (int reg = 0; reg < 4; ++reg) {
        int crow = wv * 16 + quad * 4 + reg;
#pragma unroll
        for (int nt = 0; nt < 4; ++nt)
            sC[crow * SC_STRIDE + nt * 16 + m] = (_Float16)acc4[nt][reg];
    }
    __syncthreads();
    // coalesced store first: thread -> row tid>>2, chunks (tid&3), (tid&3)+4
    {
        int r = tid >> 2, c = tid & 3;
        int grow = (int)rowbase + r;
        int p = grow / N_NODES, v = grow - p * N_NODES;
        _Float16* dst = &hwh[((size_t)v * P_PERT + p) * HDIM];
        *(f16x8*)&dst[c * 8]       = *(f16x8*)&sC[r * SC_STRIDE + c * 8];
        *(f16x8*)&dst[(c + 4) * 8] = *(f16x8*)&sC[r * SC_STRIDE + (c + 4) * 8];
    }
    // pooling last (overlaps store drain): wave pools its 16 rows from sAh
    {
        int f = lane;
        int curg = -1;
        float acc = 0.0f;
#pragma unroll
        for (int rr = 0; rr < 16; ++rr) {
            int g = bg[rr];
            if (g != curg) {
                if (curg >= 0) atomicAdd(&pooled[curg * HDIM + f], acc * (1.0f / P_PERT));
                curg = g;
                acc = 0.0f;
            }
            acc += (float)sAh[(wv * 16 + rr) * SAH_STRIDE + f];
        }
        atomicAdd(&pooled[curg * HDIM + f], acc * (1.0f / P_PERT));
    }
}

// ---------------- fused gather (all 4 perturbations per wave) ----------------
// 2 nodes/wave (grid 6250), edge loop unrolled 8-deep (VGPR 40).
// Last block (fence+ticket) folds the BN-slice reduction -> bnss.
__global__ __launch_bounds__(256) void gather_bn(const _Float16* __restrict__ hwh,
        const int* __restrict__ rowptr, const int2* __restrict__ csr,
        const float* __restrict__ dinv, const float* __restrict__ b,
        _Float16* __restrict__ h, float* __restrict__ bn,
        const float* __restrict__ gamma, const float* __restrict__ beta,
        float* __restrict__ bnss, int* __restrict__ donecnt) {
    int lane = threadIdx.x & 63;
    int wv = threadIdx.x >> 6;
    int q = lane >> 4;
    int f4 = (lane & 15) * 4;
    int loff = q * HDIM + f4;
    size_t qoff = (size_t)q * N_NODES * HDIM;
    float4 b4 = *(const float4*)&b[f4];
    float4 sum = make_float4(0.f, 0.f, 0.f, 0.f);
    float4 ssq = make_float4(0.f, 0.f, 0.f, 0.f);
#pragma unroll 1
    for (int it = 0; it < 2; ++it) {
        int v = blockIdx.x * 8 + wv * 2 + it;
        float di = dinv[v];
        float dd = di * di;
        half4 s0 = *(const half4*)&hwh[(size_t)v * 256 + loff];
        float4 acc;
        acc.x = fmaf(dd, (float)s0.x, b4.x);
        acc.y = fmaf(dd, (float)s0.y, b4.y);
        acc.z = fmaf(dd, (float)s0.z, b4.z);
        acc.w = fmaf(dd, (float)s0.w, b4.w);
        int k = rowptr[v], k1 = rowptr[v + 1];
        for (; k + 7 < k1; k += 8) {
            int2 e0 = csr[k],     e1 = csr[k + 1], e2 = csr[k + 2], e3 = csr[k + 3];
            int2 e4 = csr[k + 4], e5 = csr[k + 5], e6 = csr[k + 6], e7 = csr[k + 7];
            half4 m0 = *(const half4*)&hwh[(size_t)e0.x * 256 + loff];
            half4 m1 = *(const half4*)&hwh[(size_t)e1.x * 256 + loff];
            half4 m2 = *(const half4*)&hwh[(size_t)e2.x * 256 + loff];
            half4 m3 = *(const half4*)&hwh[(size_t)e3.x * 256 + loff];
            half4 m4 = *(const half4*)&hwh[(size_t)e4.x * 256 + loff];
            half4 m5 = *(const half4*)&hwh[(size_t)e5.x * 256 + loff];
            half4 m6 = *(const half4*)&hwh[(size_t)e6.x * 256 + loff];
            half4 m7 = *(const half4*)&hwh[(size_t)e7.x * 256 + loff];
            float w0 = __int_as_float(e0.y), w1 = __int_as_float(e1.y);
            float w2 = __int_as_float(e2.y), w3 = __int_as_float(e3.y);
            float w4 = __int_as_float(e4.y), w5 = __int_as_float(e5.y);
            float w6 = __int_as_float(e6.y), w7 = __int_as_float(e7.y);
            acc.x = fmaf(w0, (float)m0.x, acc.x); acc.y = fmaf(w0, (float)m0.y, acc.y);
            acc.z = fmaf(w0, (float)m0.z, acc.z); acc.w = fmaf(w0, (float)m0.w, acc.w);
            acc.x = fmaf(w1, (float)m1.x, acc.x); acc.y = fmaf(w1, (float)m1.y, acc.y);
            acc.z = fmaf(w1, (float)m1.z, acc.z); acc.w = fmaf(w1, (float)m1.w, acc.w);
            acc.x = fmaf(w2, (float)m2.x, acc.x); acc.y = fmaf(w2, (float)m2.y, acc.y);
            acc.z = fmaf(w2, (float)m2.z, acc.z); acc.w = fmaf(w2, (float)m2.w, acc.w);
            acc.x = fmaf(w3, (float)m3.x, acc.x); acc.y = fmaf(w3, (float)m3.y, acc.y);
            acc.z = fmaf(w3, (float)m3.z, acc.z); acc.w = fmaf(w3, (float)m3.w, acc.w);
            acc.x = fmaf(w4, (float)m4.x, acc.x); acc.y = fmaf(w4, (float)m4.y, acc.y);
            acc.z = fmaf(w4, (float)m4.z, acc.z); acc.w = fmaf(w4, (float)m4.w, acc.w);
            acc.x = fmaf(w5, (float)m5.x, acc.x); acc.y = fmaf(w5, (float)m5.y, acc.y);
            acc.z = fmaf(w5, (float)m5.z, acc.z); acc.w = fmaf(w5, (float)m5.w, acc.w);
            acc.x = fmaf(w6, (float)m6.x, acc.x); acc.y = fmaf(w6, (float)m6.y, acc.y);
            acc.z = fmaf(w6, (float)m6.z, acc.z); acc.w = fmaf(w6, (float)m6.w, acc.w);
            acc.x = fmaf(w7, (float)m7.x, acc.x); acc.y = fmaf(w7, (float)m7.y, acc.y);
            acc.z = fmaf(w7, (float)m7.z, acc.z); acc.w = fmaf(w7, (float)m7.w, acc.w);
        }
        for (; k + 3 < k1; k += 4) {
            int2 e0 = csr[k], e1 = csr[k + 1], e2 = csr[k + 2], e3 = csr[k + 3];
            half4 m0 = *(const half4*)&hwh[(size_t)e0.x * 256 + loff];
            half4 m1 = *(const half4*)&hwh[(size_t)e1.x * 256 + loff];
            half4 m2 = *(const half4*)&hwh[(size_t)e2.x * 256 + loff];
            half4 m3 = *(const half4*)&hwh[(size_t)e3.x * 256 + loff];
            float w0 = __int_as_float(e0.y), w1 = __int_as_float(e1.y);
            float w2 = __int_as_float(e2.y), w3 = __int_as_float(e3.y);
            acc.x = fmaf(w0, (float)m0.x, acc.x); acc.y = fmaf(w0, (float)m0.y, acc.y);
            acc.z = fmaf(w0, (float)m0.z, acc.z); acc.w = fmaf(w0, (float)m0.w, acc.w);
            acc.x = fmaf(w1, (float)m1.x, acc.x); acc.y = fmaf(w1, (float)m1.y, acc.y);
            acc.z = fmaf(w1, (float)m1.z, acc.z); acc.w = fmaf(w1, (float)m1.w, acc.w);
            acc.x = fmaf(w2, (float)m2.x, acc.x); acc.y = fmaf(w2, (float)m2.y, acc.y);
            acc.z = fmaf(w2, (float)m2.z, acc.z); acc.w = fmaf(w2, (float)m2.w, acc.w);
            acc.x = fmaf(w3, (float)m3.x, acc.x); acc.y = fmaf(w3, (float)m3.y, acc.y);
            acc.z = fmaf(w3, (float)m3.z, acc.z); acc.w = fmaf(w3, (float)m3.w, acc.w);
        }
        for (; k < k1; ++k) {
            int2 e0 = csr[k];
            float w0 = __int_as_float(e0.y);
            half4 m0 = *(const half4*)&hwh[(size_t)e0.x * 256 + loff];
            acc.x = fmaf(w0, (float)m0.x, acc.x); acc.y = fmaf(w0, (float)m0.y, acc.y);
            acc.z = fmaf(w0, (float)m0.z, acc.z); acc.w = fmaf(w0, (float)m0.w, acc.w);
        }
        half4 hv = {(_Float16)acc.x, (_Float16)acc.y, (_Float16)acc.z, (_Float16)acc.w};
        *(half4*)&h[qoff + (size_t)v * HDIM + f4] = hv;
        sum.x += acc.x; sum.y += acc.y; sum.z += acc.z; sum.w += acc.w;
        ssq.x = fmaf(acc.x, acc.x, ssq.x); ssq.y = fmaf(acc.y, acc.y, ssq.y);
        ssq.z = fmaf(acc.z, acc.z, ssq.z); ssq.w = fmaf(acc.w, acc.w, ssq.w);
    }
#pragma unroll
    for (int d = 16; d <= 32; d <<= 1) {
        sum.x += __shfl_xor(sum.x, d); sum.y += __shfl_xor(sum.y, d);
        sum.z += __shfl_xor(sum.z, d); sum.w += __shfl_xor(sum.w, d);
        ssq.x += __shfl_xor(ssq.x, d); ssq.y += __shfl_xor(ssq.y, d);
        ssq.z += __shfl_xor(ssq.z, d); ssq.w += __shfl_xor(ssq.w, d);
    }
    __shared__ float lsum[4][64], lssq[4][64];
    __shared__ int slast;
    if (lane < 16) {
        *(float4*)&lsum[wv][f4] = sum;
        *(float4*)&lssq[wv][f4] = ssq;
    }
    __syncthreads();
    if (threadIdx.x < 64) {
        int f = threadIdx.x;
        float s = lsum[0][f] + lsum[1][f] + lsum[2][f] + lsum[3][f];
        float qq = lssq[0][f] + lssq[1][f] + lssq[2][f] + lssq[3][f];
        float* bns = bn + (blockIdx.x & (BN_SLICES - 1)) * 128;
        atomicAdd(&bns[f], s);
        atomicAdd(&bns[64 + f], qq);
    }
    // ---- last-block BN reduction (fence + ticket) ----
    __syncthreads();   // drains this block's atomics (s_waitcnt vmcnt(0) before s_barrier)
    if (threadIdx.x == 0) {
        __threadfence();
        int ticket = atomicAdd(donecnt, 1);
        slast = (ticket == GATHER_GRID - 1);
    }
    __syncthreads();
    if (slast && threadIdx.x < 64) {
        int f = threadIdx.x;
        float su = 0.0f, sq = 0.0f;
#pragma unroll
        for (int s = 0; s < BN_SLICES; ++s) {
            su += __hip_atomic_load(&bn[s * 128 + f], __ATOMIC_RELAXED,
                                    __HIP_MEMORY_SCOPE_AGENT);
            sq += __hip_atomic_load(&bn[s * 128 + 64 + f], __ATOMIC_RELAXED,
                                    __HIP_MEMORY_SCOPE_AGENT);
        }
        const float inv_n = 1.0f / (float)NTOT;
        float mu = su * inv_n;
        float var = sq * inv_n - mu * mu;
        float sc = gamma[f] * rsqrtf(var + BN_EPS);
        bnss[f] = sc;
        bnss[64 + f] = beta[f] - mu * sc;
    }
}

// pool of last layer's activation using precomputed scale/shift
__global__ void final_pool(const _Float16* __restrict__ h, const float* __restrict__ bnss,
                           const int* __restrict__ batch, float* __restrict__ pooled) {
    int t = blockIdx.x * blockDim.x + threadIdx.x;
    if (t >= N_NODES * HDIM) return;
    int v = t >> 6, f = t & 63;
    float sc = bnss[f], sh = bnss[64 + f];
    float s = 0.0f;
#pragma unroll
    for (int p = 0; p < P_PERT; ++p) {
        size_t idx = ((size_t)(p * N_NODES + v)) * HDIM + f;
        s += fmaxf((float)h[idx] * sc + sh, 0.0f);
    }
    atomicAdd(&pooled[batch[v] * HDIM + f], s * (1.0f / P_PERT));
}

// y[g][c] = sum_i pooled_i[g] @ fc_w[i][:,c] + fc_b[i][c]; out = log_softmax(y)
__global__ void head_kernel(const float* __restrict__ pooled, const float* __restrict__ fcw,
                            const float* __restrict__ fcb, float* __restrict__ out) {
    int g = blockIdx.x;
    __shared__ float y[NCLASS];
    __shared__ float lse;
    int c = threadIdx.x;
    if (c < NCLASS) {
        float acc = 0.0f;
        for (int i = 0; i < 5; ++i) {
            acc += fcb[i * NCLASS + c];
            const float* pr = &pooled[((size_t)i * NGRAPH + g) * HDIM];
            const float* w = &fcw[i * HDIM * NCLASS + c];
            for (int k = 0; k < HDIM; ++k) acc += pr[k] * w[k * NCLASS];
        }
        y[c] = acc;
    }
    __syncthreads();
    if (threadIdx.x == 0) {
        float m = y[0];
        for (int i = 1; i < NCLASS; ++i) m = fmaxf(m, y[i]);
        float s = 0.0f;
        for (int i = 0; i < NCLASS; ++i) s += expf(y[i] - m);
        lse = m + logf(s);
    }
    __syncthreads();
    if (c < NCLASS) out[g * NCLASS + c] = y[c] - lse;
}

// ---------------- launch ----------------
extern "C" void kernel_launch(void* const* d_in, const int* in_sizes, int n_in,
                              void* d_out, int out_size, void* d_ws, size_t ws_size,
                              hipStream_t stream) {
    const float* x      = (const float*)d_in[0];
    const int*   ei     = (const int*)d_in[1];
    const int*   batch  = (const int*)d_in[2];
    const int*   mask   = (const int*)d_in[3];
    const float* conv_w = (const float*)d_in[4];
    const float* conv_b = (const float*)d_in[5];
    const float* gamma  = (const float*)d_in[6];
    const float* beta   = (const float*)d_in[7];
    const float* fcw    = (const float*)d_in[8];
    const float* fcb    = (const float*)d_in[9];
    float* out = (float*)d_out;

    char* ws = (char*)d_ws;
    // --- contiguous zeroed region [0, 1123008) (ZERO_FLOATS*4) ---
    int*      cnt     = (int*)(ws + 0);             // N ints
    int*      cursor  = (int*)(ws + 200000);        // N ints
    float*    pooled  = (float*)(ws + 400000);      // 5*512*64 f
    float*    bn      = (float*)(ws + 1055360);     // 4*32*128 f
    float*    bnss    = (float*)(ws + 1120896);     // 4*128 f -> ends 1122944
    int*      donecnt = (int*)(ws + 1122944);       // 4 ints (+pad) -> ends 1123008
    // --- rest; h/hwh 4096-aligned (512B node-group reads must not straddle) ---
    int*      rowptr  = (int*)(ws + 1123328);       // N+1 ints
    float*    dinv    = (float*)(ws + 1323520);     // N floats
    int2*     csr     = (int2*)(ws + 1523712);      // E int2 (6.4 MB)
    _Float16* h       = (_Float16*)(ws + 7925760);  // 4096-aligned; 25.6 MB
    _Float16* hwh     = (_Float16*)(ws + 33525760); // 4096-aligned; 25.6 MB
    int*      bsum    = (int*)(ws + 59125760);      // 256 ints
    int*      boff    = (int*)(ws + 59126784);      // 256 ints
    _Float16* wpack   = (_Float16*)(ws + 59127808); // 4*4096 fp16 (32 KB)

    wpack_zero_kernel<<<512, 256, 0, stream>>>(conv_w, wpack, (float*)ws);
    count_kernel<<<(N_EDGES + 255) / 256, 256, 0, stream>>>(ei, cnt);
    scan_reduce<<<SCAN_BLOCKS, 256, 0, stream>>>(cnt, bsum, dinv);
    scan_tops<<<1, 256, 0, stream>>>(bsum, boff, rowptr);
    scan_write<<<SCAN_BLOCKS, 256, 0, stream>>>(cnt, boff, rowptr);
    fill_kernel<<<(N_EDGES + 255) / 256, 256, 0, stream>>>(ei, rowptr, cursor, dinv, csr);

    for (int i = 0; i < 4; ++i) {
        float* bni = bn + i * BN_SLICES * 128;
        if (i == 0)
            gemm_fused<1><<<NTOT / 64, 256, 0, stream>>>(x, mask, nullptr,
                                                         batch, wpack, hwh, pooled);
        else
            gemm_fused<0><<<NTOT / 64, 256, 0, stream>>>(h, nullptr, bnss + (i - 1) * 128,
                                                         batch, wpack + (size_t)i * 4096,
                                                         hwh, pooled + (size_t)i * NGRAPH * HDIM);
        gather_bn<<<GATHER_GRID, 256, 0, stream>>>(hwh, rowptr, csr, dinv,
                                                   conv_b + i * HDIM, h, bni,
                                                   gamma + i * HDIM, beta + i * HDIM,
                                                   bnss + i * 128, donecnt + i);
    }
    final_pool<<<(N_NODES * HDIM + 255) / 256, 256, 0, stream>>>(
        h, bnss + 3 * 128, batch, pooled + (size_t)4 * NGRAPH * HDIM);
    head_kernel<<<NGRAPH, 64, 0, stream>>>(pooled, fcw, fcb, out);
}

// Round 18
// 506.267 us; speedup vs baseline: 2.5644x; 2.5644x over previous
//
#include <hip/hip_runtime.h>

// ---------------- problem constants ----------------
#define N_NODES 50000
#define N_EDGES 800000
#define P_PERT  4
#define NTOT    (P_PERT * N_NODES)   // 200000
#define HDIM    64
#define NGRAPH  512
#define NCLASS  10
#define BN_EPS  1e-5f
#define SCAN_BLOCKS ((N_NODES + 255) / 256)   // 196
#define BN_SLICES 32
#define SAH_STRIDE 72  // halves; 144B rows, 16B-aligned frag reads, 2-way bank alias max
#define SC_STRIDE 72   // halves
#define ZERO_FLOATS 280736          // 1122944 bytes zeroed at ws start

typedef _Float16 half4 __attribute__((ext_vector_type(4)));
typedef _Float16 f16x8 __attribute__((ext_vector_type(8)));
typedef float    f32x4 __attribute__((ext_vector_type(4)));

// Graph structure is P-independent; offset == N (verified empirically in R1).
// Gather: 2 nodes/wave + 8-deep unroll (VGPR 40, ~54% occ) is the empirical
// optimum. FETCH floor 188 MB @ ~3.5 TB/s — converged.
// R17 lesson: NO device-scope fences in the gather — __threadfence() per block
// write-back/invalidates the per-XCD L2 (non-coherent across XCDs), collapsing
// the gather's L2 service rate 3.5 -> 0.83 TB/s. Keep bn_reduce as its own
// tiny dispatch.
// R13 lesson: hwh MUST be 512B-aligned (64B-align cost 1.25x FETCH).
// R11 lesson: sBatch LDS staging diverged post-timing; batch[] via registers ok.

// ---------------- CSR build ----------------

__global__ void count_kernel(const int* __restrict__ ei, int* __restrict__ cnt) {
    int j = blockIdx.x * blockDim.x + threadIdx.x;
    if (j >= N_EDGES) return;
    atomicAdd(&cnt[ei[N_EDGES + j]], 1);
}

__global__ void scan_reduce(const int* __restrict__ cnt, int* __restrict__ bsum,
                            float* __restrict__ dinv) {
    __shared__ int sdata[256];
    int i = blockIdx.x * 256 + threadIdx.x;
    int v = (i < N_NODES) ? cnt[i] : 0;
    if (i < N_NODES) dinv[i] = rsqrtf((float)v + 1.0f);
    sdata[threadIdx.x] = v;
    __syncthreads();
    for (int off = 128; off > 0; off >>= 1) {
        if (threadIdx.x < off) sdata[threadIdx.x] += sdata[threadIdx.x + off];
        __syncthreads();
    }
    if (threadIdx.x == 0) bsum[blockIdx.x] = sdata[0];
}

__global__ void scan_tops(const int* __restrict__ bsum, int* __restrict__ boff,
                          int* __restrict__ rowptr) {
    __shared__ int sdata[256];
    int t = threadIdx.x;
    int v = (t < SCAN_BLOCKS) ? bsum[t] : 0;
    sdata[t] = v;
    __syncthreads();
    for (int off = 1; off < 256; off <<= 1) {
        int tmp = (t >= off) ? sdata[t - off] : 0;
        __syncthreads();
        sdata[t] += tmp;
        __syncthreads();
    }
    if (t < SCAN_BLOCKS) boff[t] = sdata[t] - v;
    if (t == 255) rowptr[N_NODES] = sdata[255];
}

__global__ void scan_write(const int* __restrict__ cnt, const int* __restrict__ boff,
                           int* __restrict__ rowptr) {
    __shared__ int sdata[256];
    int i = blockIdx.x * 256 + threadIdx.x;
    int v = (i < N_NODES) ? cnt[i] : 0;
    sdata[threadIdx.x] = v;
    __syncthreads();
    for (int off = 1; off < 256; off <<= 1) {
        int tmp = (threadIdx.x >= off) ? sdata[threadIdx.x - off] : 0;
        __syncthreads();
        sdata[threadIdx.x] += tmp;
        __syncthreads();
    }
    if (i < N_NODES) rowptr[i] = boff[blockIdx.x] + sdata[threadIdx.x] - v;
}

__global__ void fill_kernel(const int* __restrict__ ei, const int* __restrict__ rowptr,
                            int* __restrict__ cursor, const float* __restrict__ dinv,
                            int2* __restrict__ csr) {
    int j = blockIdx.x * blockDim.x + threadIdx.x;
    if (j >= N_EDGES) return;
    int s = ei[j], d = ei[N_EDGES + j];
    int pos = rowptr[d] + atomicAdd(&cursor[d], 1);
    csr[pos] = make_int2(s, __float_as_int(dinv[s] * dinv[d]));
}

// repack conv_w into B-fragment order (fp16) AND zero the ws accumulator region
__global__ void wpack_zero_kernel(const float* __restrict__ W, _Float16* __restrict__ wpack,
                                  float* __restrict__ zreg) {
    int idx = blockIdx.x * 256 + threadIdx.x;
    if (idx < 4 * 4096) {
        int e = idx & 4095;
        int j = e & 7;
        int lane = (e >> 3) & 63;
        int ntkh = e >> 9;
        int kh = ntkh >> 2, nt = ntkh & 3;
        int m = lane & 15, quad = lane >> 4;
        wpack[idx] = (_Float16)W[(idx >> 12) * 4096 + (kh * 32 + quad * 8 + j) * 64 + nt * 16 + m];
    }
    for (int i = idx; i < ZERO_FLOATS; i += gridDim.x * 256) zreg[i] = 0.0f;
}

// reduce 32 BN slices + gamma/beta -> bnss = {scale[64], shift[64]} (once/layer)
__global__ void bn_reduce(const float* __restrict__ bn, const float* __restrict__ gamma,
                          const float* __restrict__ beta, float* __restrict__ bnss) {
    int f = threadIdx.x;
    if (f >= 64) return;
    float su = 0.0f, sq = 0.0f;
    for (int s = 0; s < BN_SLICES; ++s) {
        su += bn[s * 128 + f];
        sq += bn[s * 128 + 64 + f];
    }
    const float inv_n = 1.0f / (float)NTOT;
    float mu = su * inv_n;
    float var = sq * inv_n - mu * mu;
    float sc = gamma[f] * rsqrtf(var + BN_EPS);
    bnss[f] = sc;
    bnss[64 + f] = beta[f] - mu * sc;
}

// ---------------- fused GEMM (MFMA, packed W) ----------------
template <int LAYER0>
__global__ __launch_bounds__(256) void gemm_fused(const void* __restrict__ srcv,
        const int* __restrict__ mask, const float* __restrict__ bnss,
        const int* __restrict__ batch, const _Float16* __restrict__ wpack,
        _Float16* __restrict__ hwh, float* __restrict__ pooled) {
    __shared__ _Float16 sAh[64 * SAH_STRIDE];
    __shared__ _Float16 sC[64 * SC_STRIDE];
    int tid = threadIdx.x;
    size_t rowbase = (size_t)blockIdx.x * 64;
    int lane = tid & 63;
    int wv = tid >> 6;
    // batch values for this wave's 16 pooled rows: wave-uniform scalar loads,
    // issued up-front so latency hides under A-staging + MFMA.
    int bg[16];
#pragma unroll
    for (int rr = 0; rr < 16; ++rr)
        bg[rr] = batch[(int)((rowbase + wv * 16 + rr) % N_NODES)];
    // B frags: coalesced f16x8 loads from packed W (16 KB, L2-hot)
    const f16x8* wp = (const f16x8*)wpack;
    f16x8 bfrag[2][4];
#pragma unroll
    for (int kh = 0; kh < 2; ++kh)
#pragma unroll
        for (int nt = 0; nt < 4; ++nt)
            bfrag[kh][nt] = wp[(kh * 4 + nt) * 64 + lane];
    // A staging (fp16): thread -> (row r0 + it*16, features f4..f4+3)
    int r0 = tid >> 4;
    int f4l = (tid & 15) * 4;
    float4 sc4, sh4;
    if (!LAYER0) {
        sc4 = *(const float4*)&bnss[f4l];
        sh4 = *(const float4*)&bnss[64 + f4l];
    }
#pragma unroll
    for (int it = 0; it < 4; ++it) {
        int r = r0 + it * 16;
        int grow = (int)rowbase + r;
        float4 val;
        if (LAYER0) {
            const float* src = (const float*)srcv;
            int p = grow / N_NODES, v = grow - p * N_NODES;
            if (mask[p * N_NODES + v]) {
                val = make_float4(0.f, 0.f, 0.f, 0.f);
            } else {
                val = *(const float4*)&src[(size_t)v * HDIM + f4l];
            }
        } else {
            const _Float16* src = (const _Float16*)srcv;
            half4 hv = *(const half4*)&src[(size_t)grow * HDIM + f4l];
            val.x = fmaxf((float)hv.x * sc4.x + sh4.x, 0.0f);
            val.y = fmaxf((float)hv.y * sc4.y + sh4.y, 0.0f);
            val.z = fmaxf((float)hv.z * sc4.z + sh4.z, 0.0f);
            val.w = fmaxf((float)hv.w * sc4.w + sh4.w, 0.0f);
        }
        half4 hv4 = {(_Float16)val.x, (_Float16)val.y, (_Float16)val.z, (_Float16)val.w};
        *(half4*)&sAh[r * SAH_STRIDE + f4l] = hv4;
    }
    __syncthreads();
    // MFMA: wave wv owns rows wv*16..wv*16+15; A-frag = one ds_read_b128 per kh
    int m = lane & 15;
    int quad = lane >> 4;
    f32x4 acc4[4];
#pragma unroll
    for (int nt = 0; nt < 4; ++nt) acc4[nt] = (f32x4){0.f, 0.f, 0.f, 0.f};
#pragma unroll
    for (int kh = 0; kh < 2; ++kh) {
        f16x8 a = *(const f16x8*)&sAh[(wv * 16 + m) * SAH_STRIDE + kh * 32 + quad * 8];
#pragma unroll
        for (int nt = 0; nt < 4; ++nt)
            acc4[nt] = __builtin_amdgcn_mfma_f32_16x16x32_f16(a, bfrag[kh][nt], acc4[nt], 0, 0, 0);
    }
    // C frag layout: col = nt*16+m, row(in 16-tile) = quad*4+reg -> stage to sC
#pragma unroll
    for (int reg = 0; reg < 4; ++reg) {
        int crow = wv * 16 + quad * 4 + reg;
#pragma unroll
        for (int nt = 0; nt < 4; ++nt)
            sC[crow * SC_STRIDE + nt * 16 + m] = (_Float16)acc4[nt][reg];
    }
    __syncthreads();
    // coalesced store first: thread -> row tid>>2, chunks (tid&3), (tid&3)+4
    {
        int r = tid >> 2, c = tid & 3;
        int grow = (int)rowbase + r;
        int p = grow / N_NODES, v = grow - p * N_NODES;
        _Float16* dst = &hwh[((size_t)v * P_PERT + p) * HDIM];
        *(f16x8*)&dst[c * 8]       = *(f16x8*)&sC[r * SC_STRIDE + c * 8];
        *(f16x8*)&dst[(c + 4) * 8] = *(f16x8*)&sC[r * SC_STRIDE + (c + 4) * 8];
    }
    // pooling last (overlaps store drain): wave pools its 16 rows from sAh
    {
        int f = lane;
        int curg = -1;
        float acc = 0.0f;
#pragma unroll
        for (int rr = 0; rr < 16; ++rr) {
            int g = bg[rr];
            if (g != curg) {
                if (curg >= 0) atomicAdd(&pooled[curg * HDIM + f], acc * (1.0f / P_PERT));
                curg = g;
                acc = 0.0f;
            }
            acc += (float)sAh[(wv * 16 + rr) * SAH_STRIDE + f];
        }
        atomicAdd(&pooled[curg * HDIM + f], acc * (1.0f / P_PERT));
    }
}

// ---------------- fused gather (all 4 perturbations per wave) ----------------
// R16 config: 2 nodes/wave (grid 6250), edge loop unrolled 8-deep (VGPR 40).
__global__ __launch_bounds__(256) void gather_bn(const _Float16* __restrict__ hwh,
        const int* __restrict__ rowptr, const int2* __restrict__ csr,
        const float* __restrict__ dinv, const float* __restrict__ b,
        _Float16* __restrict__ h, float* __restrict__ bn) {
    int lane = threadIdx.x & 63;
    int wv = threadIdx.x >> 6;
    int q = lane >> 4;
    int f4 = (lane & 15) * 4;
    int loff = q * HDIM + f4;
    size_t qoff = (size_t)q * N_NODES * HDIM;
    float4 b4 = *(const float4*)&b[f4];
    float4 sum = make_float4(0.f, 0.f, 0.f, 0.f);
    float4 ssq = make_float4(0.f, 0.f, 0.f, 0.f);
#pragma unroll 1
    for (int it = 0; it < 2; ++it) {
        int v = blockIdx.x * 8 + wv * 2 + it;
        float di = dinv[v];
        float dd = di * di;
        half4 s0 = *(const half4*)&hwh[(size_t)v * 256 + loff];
        float4 acc;
        acc.x = fmaf(dd, (float)s0.x, b4.x);
        acc.y = fmaf(dd, (float)s0.y, b4.y);
        acc.z = fmaf(dd, (float)s0.z, b4.z);
        acc.w = fmaf(dd, (float)s0.w, b4.w);
        int k = rowptr[v], k1 = rowptr[v + 1];
        for (; k + 7 < k1; k += 8) {
            int2 e0 = csr[k],     e1 = csr[k + 1], e2 = csr[k + 2], e3 = csr[k + 3];
            int2 e4 = csr[k + 4], e5 = csr[k + 5], e6 = csr[k + 6], e7 = csr[k + 7];
            half4 m0 = *(const half4*)&hwh[(size_t)e0.x * 256 + loff];
            half4 m1 = *(const half4*)&hwh[(size_t)e1.x * 256 + loff];
            half4 m2 = *(const half4*)&hwh[(size_t)e2.x * 256 + loff];
            half4 m3 = *(const half4*)&hwh[(size_t)e3.x * 256 + loff];
            half4 m4 = *(const half4*)&hwh[(size_t)e4.x * 256 + loff];
            half4 m5 = *(const half4*)&hwh[(size_t)e5.x * 256 + loff];
            half4 m6 = *(const half4*)&hwh[(size_t)e6.x * 256 + loff];
            half4 m7 = *(const half4*)&hwh[(size_t)e7.x * 256 + loff];
            float w0 = __int_as_float(e0.y), w1 = __int_as_float(e1.y);
            float w2 = __int_as_float(e2.y), w3 = __int_as_float(e3.y);
            float w4 = __int_as_float(e4.y), w5 = __int_as_float(e5.y);
            float w6 = __int_as_float(e6.y), w7 = __int_as_float(e7.y);
            acc.x = fmaf(w0, (float)m0.x, acc.x); acc.y = fmaf(w0, (float)m0.y, acc.y);
            acc.z = fmaf(w0, (float)m0.z, acc.z); acc.w = fmaf(w0, (float)m0.w, acc.w);
            acc.x = fmaf(w1, (float)m1.x, acc.x); acc.y = fmaf(w1, (float)m1.y, acc.y);
            acc.z = fmaf(w1, (float)m1.z, acc.z); acc.w = fmaf(w1, (float)m1.w, acc.w);
            acc.x = fmaf(w2, (float)m2.x, acc.x); acc.y = fmaf(w2, (float)m2.y, acc.y);
            acc.z = fmaf(w2, (float)m2.z, acc.z); acc.w = fmaf(w2, (float)m2.w, acc.w);
            acc.x = fmaf(w3, (float)m3.x, acc.x); acc.y = fmaf(w3, (float)m3.y, acc.y);
            acc.z = fmaf(w3, (float)m3.z, acc.z); acc.w = fmaf(w3, (float)m3.w, acc.w);
            acc.x = fmaf(w4, (float)m4.x, acc.x); acc.y = fmaf(w4, (float)m4.y, acc.y);
            acc.z = fmaf(w4, (float)m4.z, acc.z); acc.w = fmaf(w4, (float)m4.w, acc.w);
            acc.x = fmaf(w5, (float)m5.x, acc.x); acc.y = fmaf(w5, (float)m5.y, acc.y);
            acc.z = fmaf(w5, (float)m5.z, acc.z); acc.w = fmaf(w5, (float)m5.w, acc.w);
            acc.x = fmaf(w6, (float)m6.x, acc.x); acc.y = fmaf(w6, (float)m6.y, acc.y);
            acc.z = fmaf(w6, (float)m6.z, acc.z); acc.w = fmaf(w6, (float)m6.w, acc.w);
            acc.x = fmaf(w7, (float)m7.x, acc.x); acc.y = fmaf(w7, (float)m7.y, acc.y);
            acc.z = fmaf(w7, (float)m7.z, acc.z); acc.w = fmaf(w7, (float)m7.w, acc.w);
        }
        for (; k + 3 < k1; k += 4) {
            int2 e0 = csr[k], e1 = csr[k + 1], e2 = csr[k + 2], e3 = csr[k + 3];
            half4 m0 = *(const half4*)&hwh[(size_t)e0.x * 256 + loff];
            half4 m1 = *(const half4*)&hwh[(size_t)e1.x * 256 + loff];
            half4 m2 = *(const half4*)&hwh[(size_t)e2.x * 256 + loff];
            half4 m3 = *(const half4*)&hwh[(size_t)e3.x * 256 + loff];
            float w0 = __int_as_float(e0.y), w1 = __int_as_float(e1.y);
            float w2 = __int_as_float(e2.y), w3 = __int_as_float(e3.y);
            acc.x = fmaf(w0, (float)m0.x, acc.x); acc.y = fmaf(w0, (float)m0.y, acc.y);
            acc.z = fmaf(w0, (float)m0.z, acc.z); acc.w = fmaf(w0, (float)m0.w, acc.w);
            acc.x = fmaf(w1, (float)m1.x, acc.x); acc.y = fmaf(w1, (float)m1.y, acc.y);
            acc.z = fmaf(w1, (float)m1.z, acc.z); acc.w = fmaf(w1, (float)m1.w, acc.w);
            acc.x = fmaf(w2, (float)m2.x, acc.x); acc.y = fmaf(w2, (float)m2.y, acc.y);
            acc.z = fmaf(w2, (float)m2.z, acc.z); acc.w = fmaf(w2, (float)m2.w, acc.w);
            acc.x = fmaf(w3, (float)m3.x, acc.x); acc.y = fmaf(w3, (float)m3.y, acc.y);
            acc.z = fmaf(w3, (float)m3.z, acc.z); acc.w = fmaf(w3, (float)m3.w, acc.w);
        }
        for (; k < k1; ++k) {
            int2 e0 = csr[k];
            float w0 = __int_as_float(e0.y);
            half4 m0 = *(const half4*)&hwh[(size_t)e0.x * 256 + loff];
            acc.x = fmaf(w0, (float)m0.x, acc.x); acc.y = fmaf(w0, (float)m0.y, acc.y);
            acc.z = fmaf(w0, (float)m0.z, acc.z); acc.w = fmaf(w0, (float)m0.w, acc.w);
        }
        half4 hv = {(_Float16)acc.x, (_Float16)acc.y, (_Float16)acc.z, (_Float16)acc.w};
        *(half4*)&h[qoff + (size_t)v * HDIM + f4] = hv;
        sum.x += acc.x; sum.y += acc.y; sum.z += acc.z; sum.w += acc.w;
        ssq.x = fmaf(acc.x, acc.x, ssq.x); ssq.y = fmaf(acc.y, acc.y, ssq.y);
        ssq.z = fmaf(acc.z, acc.z, ssq.z); ssq.w = fmaf(acc.w, acc.w, ssq.w);
    }
#pragma unroll
    for (int d = 16; d <= 32; d <<= 1) {
        sum.x += __shfl_xor(sum.x, d); sum.y += __shfl_xor(sum.y, d);
        sum.z += __shfl_xor(sum.z, d); sum.w += __shfl_xor(sum.w, d);
        ssq.x += __shfl_xor(ssq.x, d); ssq.y += __shfl_xor(ssq.y, d);
        ssq.z += __shfl_xor(ssq.z, d); ssq.w += __shfl_xor(ssq.w, d);
    }
    __shared__ float lsum[4][64], lssq[4][64];
    if (lane < 16) {
        *(float4*)&lsum[wv][f4] = sum;
        *(float4*)&lssq[wv][f4] = ssq;
    }
    __syncthreads();
    if (threadIdx.x < 64) {
        int f = threadIdx.x;
        float s = lsum[0][f] + lsum[1][f] + lsum[2][f] + lsum[3][f];
        float qq = lssq[0][f] + lssq[1][f] + lssq[2][f] + lssq[3][f];
        float* bns = bn + (blockIdx.x & (BN_SLICES - 1)) * 128;
        atomicAdd(&bns[f], s);
        atomicAdd(&bns[64 + f], qq);
    }
}

// pool of last layer's activation using precomputed scale/shift
__global__ void final_pool(const _Float16* __restrict__ h, const float* __restrict__ bnss,
                           const int* __restrict__ batch, float* __restrict__ pooled) {
    int t = blockIdx.x * blockDim.x + threadIdx.x;
    if (t >= N_NODES * HDIM) return;
    int v = t >> 6, f = t & 63;
    float sc = bnss[f], sh = bnss[64 + f];
    float s = 0.0f;
#pragma unroll
    for (int p = 0; p < P_PERT; ++p) {
        size_t idx = ((size_t)(p * N_NODES + v)) * HDIM + f;
        s += fmaxf((float)h[idx] * sc + sh, 0.0f);
    }
    atomicAdd(&pooled[batch[v] * HDIM + f], s * (1.0f / P_PERT));
}

// y[g][c] = sum_i pooled_i[g] @ fc_w[i][:,c] + fc_b[i][c]; out = log_softmax(y)
__global__ void head_kernel(const float* __restrict__ pooled, const float* __restrict__ fcw,
                            const float* __restrict__ fcb, float* __restrict__ out) {
    int g = blockIdx.x;
    __shared__ float y[NCLASS];
    __shared__ float lse;
    int c = threadIdx.x;
    if (c < NCLASS) {
        float acc = 0.0f;
        for (int i = 0; i < 5; ++i) {
            acc += fcb[i * NCLASS + c];
            const float* pr = &pooled[((size_t)i * NGRAPH + g) * HDIM];
            const float* w = &fcw[i * HDIM * NCLASS + c];
            for (int k = 0; k < HDIM; ++k) acc += pr[k] * w[k * NCLASS];
        }
        y[c] = acc;
    }
    __syncthreads();
    if (threadIdx.x == 0) {
        float m = y[0];
        for (int i = 1; i < NCLASS; ++i) m = fmaxf(m, y[i]);
        float s = 0.0f;
        for (int i = 0; i < NCLASS; ++i) s += expf(y[i] - m);
        lse = m + logf(s);
    }
    __syncthreads();
    if (c < NCLASS) out[g * NCLASS + c] = y[c] - lse;
}

// ---------------- launch ----------------
extern "C" void kernel_launch(void* const* d_in, const int* in_sizes, int n_in,
                              void* d_out, int out_size, void* d_ws, size_t ws_size,
                              hipStream_t stream) {
    const float* x      = (const float*)d_in[0];
    const int*   ei     = (const int*)d_in[1];
    const int*   batch  = (const int*)d_in[2];
    const int*   mask   = (const int*)d_in[3];
    const float* conv_w = (const float*)d_in[4];
    const float* conv_b = (const float*)d_in[5];
    const float* gamma  = (const float*)d_in[6];
    const float* beta   = (const float*)d_in[7];
    const float* fcw    = (const float*)d_in[8];
    const float* fcb    = (const float*)d_in[9];
    float* out = (float*)d_out;

    char* ws = (char*)d_ws;
    // --- contiguous zeroed region [0, 1122944) (ZERO_FLOATS*4) ---
    int*      cnt     = (int*)(ws + 0);             // N ints
    int*      cursor  = (int*)(ws + 200000);        // N ints
    float*    pooled  = (float*)(ws + 400000);      // 5*512*64 f
    float*    bn      = (float*)(ws + 1055360);     // 4*32*128 f
    float*    bnss    = (float*)(ws + 1120896);     // 4*128 f -> ends 1122944
    // --- rest; h/hwh 4096-aligned (512B node-group reads must not straddle) ---
    int*      rowptr  = (int*)(ws + 1123328);       // N+1 ints
    float*    dinv    = (float*)(ws + 1323520);     // N floats
    int2*     csr     = (int2*)(ws + 1523712);      // E int2 (6.4 MB)
    _Float16* h       = (_Float16*)(ws + 7925760);  // 4096-aligned; 25.6 MB
    _Float16* hwh     = (_Float16*)(ws + 33525760); // 4096-aligned; 25.6 MB
    int*      bsum    = (int*)(ws + 59125760);      // 256 ints
    int*      boff    = (int*)(ws + 59126784);      // 256 ints
    _Float16* wpack   = (_Float16*)(ws + 59127808); // 4*4096 fp16 (32 KB)

    wpack_zero_kernel<<<512, 256, 0, stream>>>(conv_w, wpack, (float*)ws);
    count_kernel<<<(N_EDGES + 255) / 256, 256, 0, stream>>>(ei, cnt);
    scan_reduce<<<SCAN_BLOCKS, 256, 0, stream>>>(cnt, bsum, dinv);
    scan_tops<<<1, 256, 0, stream>>>(bsum, boff, rowptr);
    scan_write<<<SCAN_BLOCKS, 256, 0, stream>>>(cnt, boff, rowptr);
    fill_kernel<<<(N_EDGES + 255) / 256, 256, 0, stream>>>(ei, rowptr, cursor, dinv, csr);

    const int gather_grid = N_NODES / 8;   // 6250 blocks, 2 nodes/wave
    for (int i = 0; i < 4; ++i) {
        float* bni = bn + i * BN_SLICES * 128;
        if (i == 0)
            gemm_fused<1><<<NTOT / 64, 256, 0, stream>>>(x, mask, nullptr,
                                                         batch, wpack, hwh, pooled);
        else
            gemm_fused<0><<<NTOT / 64, 256, 0, stream>>>(h, nullptr, bnss + (i - 1) * 128,
                                                         batch, wpack + (size_t)i * 4096,
                                                         hwh, pooled + (size_t)i * NGRAPH * HDIM);
        gather_bn<<<gather_grid, 256, 0, stream>>>(hwh, rowptr, csr, dinv,
                                                   conv_b + i * HDIM, h, bni);
        bn_reduce<<<1, 64, 0, stream>>>(bni, gamma + i * HDIM, beta + i * HDIM,
                                        bnss + i * 128);
    }
    final_pool<<<(N_NODES * HDIM + 255) / 256, 256, 0, stream>>>(
        h, bnss + 3 * 128, batch, pooled + (size_t)4 * NGRAPH * HDIM);
    head_kernel<<<NGRAPH, 64, 0, stream>>>(pooled, fcw, fcb, out);
}